// Round 5
// baseline (302.830 us; speedup 1.0000x reference)
//
#include <hip/hip_runtime.h>
#include <hip/hip_bf16.h>
#include <cstddef>

#define B_   128
#define L_   128
#define H_   1024
#define V_   50000
#define INDIM 1088   // H + 32 + 32

typedef short short8 __attribute__((ext_vector_type(8)));
typedef unsigned short ushort4v __attribute__((ext_vector_type(4)));
typedef float f32x4 __attribute__((ext_vector_type(4)));

static __device__ __forceinline__ unsigned short f2bf(float f) {
    unsigned u = __builtin_bit_cast(unsigned, f);
    u = u + 0x7FFFu + ((u >> 16) & 1u);
    return (unsigned short)(u >> 16);
}
static __device__ __forceinline__ float bf2f(unsigned short h) {
    unsigned u = ((unsigned)h) << 16;
    return __builtin_bit_cast(float, u);
}
static __device__ __forceinline__ float sigm(float v) {
    return 1.f / (1.f + __expf(-v));
}

// packed f32x2 -> bf16x2 (RNE), gfx950 HW instruction
static __device__ __forceinline__ unsigned cvt_pk(float lo, float hi) {
    unsigned r;
    asm("v_cvt_pk_bf16_f32 %0, %1, %2" : "=v"(r) : "v"(lo), "v"(hi));
    return r;
}
// 8 f32 -> short8 bf16 (hi plane only)
static __device__ __forceinline__ short8 cvt8(float4 a, float4 b) {
    union { unsigned u[4]; short8 s; } r;
    r.u[0] = cvt_pk(a.x, a.y); r.u[1] = cvt_pk(a.z, a.w);
    r.u[2] = cvt_pk(b.x, b.y); r.u[3] = cvt_pk(b.z, b.w);
    return r.s;
}
// 8 f32 -> hi + lo bf16 planes (split-f32)
static __device__ __forceinline__ void cvt8_split(float4 a, float4 b, short8& hi, short8& lo) {
    const float f[8] = {a.x, a.y, a.z, a.w, b.x, b.y, b.z, b.w};
    union { unsigned u[4]; short8 s; } rh, rl;
#pragma unroll
    for (int i = 0; i < 4; i++) {
        const unsigned p = cvt_pk(f[2 * i], f[2 * i + 1]);
        const float r0 = __builtin_bit_cast(float, p << 16);
        const float r1 = __builtin_bit_cast(float, p & 0xFFFF0000u);
        rh.u[i] = p;
        rl.u[i] = cvt_pk(f[2 * i] - r0, f[2 * i + 1] - r1);
    }
    hi = rh.s; lo = rl.s;
}

#define MFMA(a, b, c) __builtin_amdgcn_mfma_f32_16x16x32_bf16((a), (b), (c), 0, 0, 0)

// ---------------------------------------------------------------------------
// prep (blocks 0..127): x/h bf16 hi+lo planes.
// transpose (blocks 128..383): Wt[n][k] = W_attn[k][n] as bf16 hi/lo planes.
// ---------------------------------------------------------------------------
__global__ __launch_bounds__(256) void prep_kernel(
    const int* __restrict__ seq, const int* __restrict__ c2n,
    const int* __restrict__ c2f, const float* __restrict__ emb,
    const float* __restrict__ semb, const float* __restrict__ nemb,
    const float* __restrict__ lh, const float* __restrict__ W_attn,
    unsigned short* __restrict__ x_hi, unsigned short* __restrict__ x_lo,
    unsigned short* __restrict__ h_hi, unsigned short* __restrict__ h_lo,
    unsigned short* __restrict__ wt_hi, unsigned short* __restrict__ wt_lo)
{
    __shared__ float tile[64][65];
    const int t = threadIdx.x;
    if (blockIdx.x < 128) {
        const int b = blockIdx.x;
        const int idx = seq[b];
        for (int i = t; i < 528; i += 256) {
            float4 v;
            unsigned short *dh, *dl;
            int off;
            if (i < 272) {
                if (i < 256) {
                    v = *(const float4*)&emb[(size_t)idx * H_ + i * 4];
                } else {
                    const int j = i - 256;
                    if (j < 8) v = *(const float4*)&semb[c2f[idx] * 32 + j * 4];
                    else       v = *(const float4*)&nemb[c2n[idx] * 32 + (j - 8) * 4];
                }
                dh = x_hi + (size_t)b * INDIM; dl = x_lo + (size_t)b * INDIM; off = i * 4;
            } else {
                const int j = i - 272;
                v = *(const float4*)&lh[(size_t)b * H_ + j * 4];
                dh = h_hi + (size_t)b * H_; dl = h_lo + (size_t)b * H_; off = j * 4;
            }
            const float fv[4] = {v.x, v.y, v.z, v.w};
            ushort4v hh, ll;
#pragma unroll
            for (int e = 0; e < 4; e++) {
                hh[e] = f2bf(fv[e]);
                ll[e] = f2bf(fv[e] - bf2f(hh[e]));
            }
            *(ushort4v*)&dh[off] = hh;
            *(ushort4v*)&dl[off] = ll;
        }
    } else {
        const int bid = blockIdx.x - 128;         // 0..255
        const int n0 = (bid & 15) * 64, k0 = (bid >> 4) * 64;
        const int c = t & 63, r4 = t >> 6;
#pragma unroll
        for (int i = 0; i < 16; i++) {
            const int r = r4 * 16 + i;
            tile[r][c] = W_attn[(size_t)(k0 + r) * H_ + n0 + c];
        }
        __syncthreads();
#pragma unroll
        for (int i = 0; i < 16; i++) {
            const int r = r4 * 16 + i;
            const float f = tile[c][r];           // = W_attn[k0+c][n0+r]
            const unsigned short hb = f2bf(f);
            wt_hi[(size_t)(n0 + r) * H_ + k0 + c] = hb;
            wt_lo[(size_t)(n0 + r) * H_ + k0 + c] = f2bf(f - bf2f(hb));
        }
    }
}

// ---------------------------------------------------------------------------
// waveGEMM: one wave owns a 128x16 output slab (8 MFMA fragments), zero LDS,
// zero barriers. A = bf16 plane(s) [128][lda]; B = W rows (f32, [N][K]) or
// pre-converted bf16 planes. Fragment loads land directly in MFMA layout:
//   A frag (mi,ks): lane reads Ah[(mi*16 + l15)*lda + k], 8 bf16
//   B frag (ks):    lane reads W[(n0+l15)*ldw + k], 8 f32 -> cvt_pk
//   k = k0 + ks*32 + (lane>>4)*8
// ---------------------------------------------------------------------------

// split-accuracy, B from f32 (gi & gh merged: tile<192 -> gi, else gh)
__global__ __launch_bounds__(256) void gru_wgemm(
    const unsigned short* __restrict__ x_hi, const unsigned short* __restrict__ x_lo,
    const float* __restrict__ W_ih,
    const unsigned short* __restrict__ h_hi, const unsigned short* __restrict__ h_lo,
    const float* __restrict__ W_hh,
    float* __restrict__ gi, float* __restrict__ gh)
{
    const int wid = blockIdx.x * 4 + (threadIdx.x >> 6);
    const int lane = threadIdx.x & 63, l15 = lane & 15, g = lane >> 4;
    const int y = wid & 3;
    int tile = wid >> 2;
    const unsigned short *Ah, *Al;
    const float* W;
    float* Cp;
    int lda, K0, KL;
    if (tile < 192) {
        Ah = x_hi; Al = x_lo; W = W_ih; Cp = gi; lda = INDIM;
        K0 = y ? 320 + (y - 1) * 256 : 0; KL = y ? 256 : 320;
    } else {
        tile -= 192;
        Ah = h_hi; Al = h_lo; W = W_hh; Cp = gh; lda = H_;
        K0 = y * 256; KL = 256;
    }
    const int n0 = tile * 16;
    Cp += (size_t)y * (128 * 3072);
    const float* Wb = W + (size_t)(n0 + l15) * lda;

    f32x4 acc[8];
#pragma unroll
    for (int i = 0; i < 8; i++) acc[i] = (f32x4){0.f, 0.f, 0.f, 0.f};

    for (int k0 = K0; k0 < K0 + KL; k0 += 64) {
#pragma unroll
        for (int ks = 0; ks < 2; ks++) {
            const int k = k0 + ks * 32 + g * 8;
            const float4 w0 = *(const float4*)&Wb[k];
            const float4 w1 = *(const float4*)&Wb[k + 4];
            short8 bh, bl;
            cvt8_split(w0, w1, bh, bl);
#pragma unroll
            for (int mi = 0; mi < 8; mi++) {
                const short8 ah = *(const short8*)&Ah[(size_t)(mi * 16 + l15) * lda + k];
                const short8 al = *(const short8*)&Al[(size_t)(mi * 16 + l15) * lda + k];
                acc[mi] = MFMA(ah, bh, acc[mi]);
                acc[mi] = MFMA(ah, bl, acc[mi]);
                acc[mi] = MFMA(al, bh, acc[mi]);
            }
        }
    }
    const int col = n0 + l15;
#pragma unroll
    for (int mi = 0; mi < 8; mi++)
#pragma unroll
        for (int r = 0; r < 4; r++)
            Cp[(size_t)(mi * 16 + g * 4 + r) * 3072 + col] = acc[mi][r];
}

// split-accuracy, B already bf16 planes (q = h @ W_attn via transposed planes)
__global__ __launch_bounds__(256) void q_wgemm(
    const unsigned short* __restrict__ cat_hi, const unsigned short* __restrict__ cat_lo,
    const unsigned short* __restrict__ wt_hi, const unsigned short* __restrict__ wt_lo,
    float* __restrict__ q_part)
{
    const int wid = blockIdx.x * 4 + (threadIdx.x >> 6);   // 256 waves
    const int lane = threadIdx.x & 63, l15 = lane & 15, g = lane >> 4;
    const int y = wid & 3, tile = wid >> 2;
    const int n0 = tile * 16, K0 = y * 256;
    float* Cp = q_part + (size_t)y * (128 * 1024);
    const unsigned short* Bh = wt_hi + (size_t)(n0 + l15) * H_;
    const unsigned short* Bl = wt_lo + (size_t)(n0 + l15) * H_;

    f32x4 acc[8];
#pragma unroll
    for (int i = 0; i < 8; i++) acc[i] = (f32x4){0.f, 0.f, 0.f, 0.f};

    for (int k0 = K0; k0 < K0 + 256; k0 += 64) {
#pragma unroll
        for (int ks = 0; ks < 2; ks++) {
            const int k = k0 + ks * 32 + g * 8;
            const short8 bh = *(const short8*)&Bh[k];
            const short8 bl = *(const short8*)&Bl[k];
#pragma unroll
            for (int mi = 0; mi < 8; mi++) {
                const short8 ah = *(const short8*)&cat_hi[(size_t)(mi * 16 + l15) * 2048 + k];
                const short8 al = *(const short8*)&cat_lo[(size_t)(mi * 16 + l15) * 2048 + k];
                acc[mi] = MFMA(ah, bh, acc[mi]);
                acc[mi] = MFMA(ah, bl, acc[mi]);
                acc[mi] = MFMA(al, bh, acc[mi]);
            }
        }
    }
    const int col = n0 + l15;
#pragma unroll
    for (int mi = 0; mi < 8; mi++)
#pragma unroll
        for (int r = 0; r < 4; r++)
            Cp[(size_t)(mi * 16 + g * 4 + r) * 1024 + col] = acc[mi][r];
}

// plain bf16, B from f32: co_part = cat_hi @ W_cat.T (k-split 4x512)
__global__ __launch_bounds__(256) void cat_wgemm(
    const unsigned short* __restrict__ cat_hi, const float* __restrict__ W_cat,
    float* __restrict__ co_part)
{
    const int wid = blockIdx.x * 4 + (threadIdx.x >> 6);   // 256 waves
    const int lane = threadIdx.x & 63, l15 = lane & 15, g = lane >> 6 ? 0 : lane >> 4; // g below
    const int gg = (threadIdx.x & 63) >> 4;
    const int y = wid & 3, tile = wid >> 2;
    const int n0 = tile * 16, K0 = y * 512;
    float* Cp = co_part + (size_t)y * (128 * 1024);
    const float* Wb = W_cat + (size_t)(n0 + l15) * 2048;

    f32x4 acc[8];
#pragma unroll
    for (int i = 0; i < 8; i++) acc[i] = (f32x4){0.f, 0.f, 0.f, 0.f};

    for (int k0 = K0; k0 < K0 + 512; k0 += 64) {
#pragma unroll
        for (int ks = 0; ks < 2; ks++) {
            const int k = k0 + ks * 32 + gg * 8;
            const float4 w0 = *(const float4*)&Wb[k];
            const float4 w1 = *(const float4*)&Wb[k + 4];
            const short8 bh = cvt8(w0, w1);
#pragma unroll
            for (int mi = 0; mi < 8; mi++) {
                const short8 ah = *(const short8*)&cat_hi[(size_t)(mi * 16 + l15) * 2048 + k];
                acc[mi] = MFMA(ah, bh, acc[mi]);
            }
        }
    }
    const int col = n0 + l15;
#pragma unroll
    for (int mi = 0; mi < 8; mi++)
#pragma unroll
        for (int r = 0; r < 4; r++)
            Cp[(size_t)(mi * 16 + gg * 4 + r) * 1024 + col] = acc[mi][r];
}

// plain bf16, B from f32: out = co_hi @ W_out.T + b_out  (3125 waves)
__global__ __launch_bounds__(256) void out_wgemm(
    const unsigned short* __restrict__ co_hi, const float* __restrict__ W_out,
    const float* __restrict__ b_out, float* __restrict__ C)
{
    const int wid = blockIdx.x * 4 + (threadIdx.x >> 6);
    if (wid >= 3125) return;
    const int lane = threadIdx.x & 63, l15 = lane & 15, g = lane >> 4;
    const int n0 = wid * 16;
    const float* Wb = W_out + (size_t)(n0 + l15) * H_;

    f32x4 acc[8];
#pragma unroll
    for (int i = 0; i < 8; i++) acc[i] = (f32x4){0.f, 0.f, 0.f, 0.f};

    for (int k0 = 0; k0 < 1024; k0 += 64) {
#pragma unroll
        for (int ks = 0; ks < 2; ks++) {
            const int k = k0 + ks * 32 + g * 8;
            const float4 w0 = *(const float4*)&Wb[k];
            const float4 w1 = *(const float4*)&Wb[k + 4];
            const short8 bh = cvt8(w0, w1);
#pragma unroll
            for (int mi = 0; mi < 8; mi++) {
                const short8 ah = *(const short8*)&co_hi[(size_t)(mi * 16 + l15) * 1024 + k];
                acc[mi] = MFMA(ah, bh, acc[mi]);
            }
        }
    }
    const int col = n0 + l15;
    const float bb = b_out[col];
#pragma unroll
    for (int mi = 0; mi < 8; mi++)
#pragma unroll
        for (int r = 0; r < 4; r++)
            C[(size_t)(mi * 16 + g * 4 + r) * V_ + col] = acc[mi][r] + bb;
}

// ---------------------------------------------------------------------------
// GRU gates: sums 4 k-slice partials of gi/gh, adds biases, computes h.
// ---------------------------------------------------------------------------
__global__ __launch_bounds__(256) void gru_gates_kernel(
    const float* __restrict__ gi, const float* __restrict__ gh,
    const float* __restrict__ b_ih, const float* __restrict__ b_hh,
    const float* __restrict__ h_prev,
    float* __restrict__ hid_out,
    unsigned short* __restrict__ cat_hi, unsigned short* __restrict__ cat_lo)
{
    const int id = blockIdx.x * 256 + threadIdx.x;
    const int b = id >> 10, j = id & 1023;
    const size_t base = (size_t)b * 3072 + j;
    float ir = b_ih[j], iz = b_ih[1024 + j], in_ = b_ih[2048 + j];
    float hr = b_hh[j], hz = b_hh[1024 + j], hn = b_hh[2048 + j];
#pragma unroll
    for (int p = 0; p < 4; p++) {
        const float* gp = gi + (size_t)p * (128 * 3072);
        const float* hp = gh + (size_t)p * (128 * 3072);
        ir += gp[base]; iz += gp[base + 1024]; in_ += gp[base + 2048];
        hr += hp[base]; hz += hp[base + 1024]; hn += hp[base + 2048];
    }
    const float r = sigm(ir + hr);
    const float z = sigm(iz + hz);
    const float n = tanhf(in_ + r * hn);
    const float h = (1.f - z) * n + z * h_prev[id];
    hid_out[id] = h;
    const unsigned short hb = f2bf(h);
    cat_hi[(size_t)b * 2048 + j] = hb;
    cat_lo[(size_t)b * 2048 + j] = f2bf(h - bf2f(hb));
}

// ---------------------------------------------------------------------------
// energies (partial over 4 h-slices); 512 thr = 8 waves, 16 l each.
// ---------------------------------------------------------------------------
__global__ __launch_bounds__(512) void energy_partial_kernel(
    const float* __restrict__ qp, const float* __restrict__ enc,
    float* __restrict__ epart)
{
    const int s = blockIdx.x, b = blockIdx.y;
    const int t = threadIdx.x, lane = t & 63, wv = t >> 6;
    __shared__ float q_s[256];
    if (t < 256) {
        const size_t o = (size_t)b * H_ + s * 256 + t;
        q_s[t] = qp[o] + qp[o + 131072] + qp[o + 262144] + qp[o + 393216];
    }
    __syncthreads();
    const float4 qv = *(const float4*)&q_s[lane * 4];
    const float* encb = enc + (size_t)b * H_ + s * 256;
    for (int l0 = 0; l0 < 16; l0++) {
        const int l = wv * 16 + l0;
        float4 ev = *(const float4*)&encb[(size_t)l * (B_ * H_) + lane * 4];
        float p = ev.x * qv.x + ev.y * qv.y + ev.z * qv.z + ev.w * qv.w;
#pragma unroll
        for (int off = 32; off > 0; off >>= 1) p += __shfl_xor(p, off);
        if (lane == 0) epart[((size_t)b * 128 + l) * 4 + s] = p;
    }
}

// ---------------------------------------------------------------------------
// Fused softmax + context; s==0 writes attnw.
// ---------------------------------------------------------------------------
__global__ __launch_bounds__(256) void context_softmax_kernel(
    const float* __restrict__ epart, const float* __restrict__ enc,
    unsigned short* __restrict__ cat_hi, float* __restrict__ attnw)
{
    const int s = blockIdx.x, b = blockIdx.y, t = threadIdx.x;
    const int lane = t & 63, wv = t >> 6;
    __shared__ float w_s[128];
    __shared__ float red[4];

    float e = -INFINITY;
    if (t < 128) {
        float4 pe = *(const float4*)&epart[((size_t)b * 128 + t) * 4];
        e = pe.x + pe.y + pe.z + pe.w;
    }
    float mx = e;
#pragma unroll
    for (int off = 32; off > 0; off >>= 1) mx = fmaxf(mx, __shfl_xor(mx, off));
    if (lane == 0) red[wv] = mx;
    __syncthreads();
    const float gm = fmaxf(fmaxf(red[0], red[1]), fmaxf(red[2], red[3]));
    __syncthreads();
    float ex = (t < 128) ? __expf(e - gm) : 0.f;
    float sm = ex;
#pragma unroll
    for (int off = 32; off > 0; off >>= 1) sm += __shfl_xor(sm, off);
    if (lane == 0) red[wv] = sm;
    __syncthreads();
    const float gs = red[0] + red[1] + red[2] + red[3];
    if (t < 128) {
        const float w = ex / gs;
        w_s[t] = w;
        if (s == 0) attnw[(size_t)b * L_ + t] = w;
    }
    __syncthreads();

    const int h = s * 256 + t;
    const float* encb = enc + (size_t)b * H_ + h;
    float c = 0.f;
#pragma unroll 4
    for (int l = 0; l < 128; l++)
        c += w_s[l] * encb[(size_t)l * (B_ * H_)];
    cat_hi[(size_t)b * 2048 + 1024 + h] = f2bf(c);
}

// co = tanh(sum of 4 partials + b_cat) -> bf16
__global__ __launch_bounds__(256) void co_reduce_kernel(
    const float* __restrict__ co_part, const float* __restrict__ b_cat,
    unsigned short* __restrict__ co_hi)
{
    const int id = blockIdx.x * 256 + threadIdx.x;
    const int j = id & 1023;
    float s = b_cat[j];
#pragma unroll
    for (int p = 0; p < 4; p++) s += co_part[(size_t)p * 131072 + id];
    co_hi[id] = f2bf(tanhf(s));
}

// ---------------------------------------------------------------------------
extern "C" void kernel_launch(void* const* d_in, const int* in_sizes, int n_in,
                              void* d_out, int out_size, void* d_ws, size_t ws_size,
                              hipStream_t stream)
{
    const int*   seq    = (const int*)  d_in[0];
    const float* lh     = (const float*)d_in[1];
    const float* enc    = (const float*)d_in[2];
    const int*   c2n    = (const int*)  d_in[3];
    const int*   c2f    = (const int*)  d_in[4];
    const float* emb    = (const float*)d_in[5];
    const float* semb   = (const float*)d_in[6];
    const float* nemb   = (const float*)d_in[7];
    const float* W_ih   = (const float*)d_in[8];
    const float* W_hh   = (const float*)d_in[9];
    const float* b_ih   = (const float*)d_in[10];
    const float* b_hh   = (const float*)d_in[11];
    const float* W_attn = (const float*)d_in[12];
    // d_in[13] = b_attn: dropped (softmax shift-invariant, exact)
    const float* W_cat  = (const float*)d_in[14];
    const float* b_cat  = (const float*)d_in[15];
    const float* W_out  = (const float*)d_in[16];
    const float* b_out  = (const float*)d_in[17];

    float* out    = (float*)d_out;
    float* hidden = out + (size_t)B_ * V_;
    float* attnw  = hidden + (size_t)B_ * H_;

    // ---- workspace layout ----
    unsigned short* x_hi   = (unsigned short*)d_ws;            // 128*1088
    unsigned short* x_lo   = x_hi   + (size_t)128 * INDIM;
    unsigned short* h_hi   = x_lo   + (size_t)128 * INDIM;     // 128*1024
    unsigned short* h_lo   = h_hi   + (size_t)128 * 1024;
    unsigned short* cat_hi = h_lo   + (size_t)128 * 1024;      // 128*2048
    unsigned short* cat_lo = cat_hi + (size_t)128 * 2048;
    unsigned short* co_hi  = cat_lo + (size_t)128 * 2048;      // 128*1024
    unsigned short* wt_hi  = co_hi  + (size_t)128 * 1024;      // 1024*1024
    unsigned short* wt_lo  = wt_hi  + (size_t)1024 * 1024;     // 1024*1024
    float* fbase   = (float*)(wt_lo + (size_t)1024 * 1024);
    float* gi_part = fbase;                                    // 4*128*3072
    float* gh_part = gi_part + (size_t)4 * 128 * 3072;         // 4*128*3072
    // aliases (gi/gh dead after gates):
    float* q_part  = fbase;                                    // 4*128*1024
    float* co_part = q_part + (size_t)4 * 128 * 1024;          // 4*128*1024
    float* epart   = co_part + (size_t)4 * 128 * 1024;         // 128*128*4

    // 1. prep (x/h planes) + W_attn transpose to bf16 planes
    hipLaunchKernelGGL(prep_kernel, dim3(128 + 256), dim3(256), 0, stream,
                       seq, c2n, c2f, emb, semb, nemb, lh, W_attn,
                       x_hi, x_lo, h_hi, h_lo, wt_hi, wt_lo);
    // 2. gi & gh partials, waveGEMM: (192+192) tiles x 4 k-slices = 1536 waves
    hipLaunchKernelGGL(gru_wgemm, dim3(384), dim3(256), 0, stream,
                       x_hi, x_lo, W_ih, h_hi, h_lo, W_hh, gi_part, gh_part);
    // 3. gates -> hidden + cat planes
    hipLaunchKernelGGL(gru_gates_kernel, dim3(512), dim3(256), 0, stream,
                       gi_part, gh_part, b_ih, b_hh, lh, hidden, cat_hi, cat_lo);
    // 4. q partials, waveGEMM with bf16 B planes: 64 tiles x 4 = 256 waves
    hipLaunchKernelGGL(q_wgemm, dim3(64), dim3(256), 0, stream,
                       cat_hi, cat_lo, wt_hi, wt_lo, q_part);
    // 5. energies
    hipLaunchKernelGGL(energy_partial_kernel, dim3(4, 128), dim3(512), 0, stream,
                       q_part, enc, epart);
    // 6. softmax + context fused
    hipLaunchKernelGGL(context_softmax_kernel, dim3(4, 128), dim3(256), 0, stream,
                       epart, enc, cat_hi, attnw);
    // 7. co partials, waveGEMM: 64 tiles x 4 k-slices = 256 waves
    hipLaunchKernelGGL(cat_wgemm, dim3(64), dim3(256), 0, stream,
                       cat_hi, W_cat, co_part);
    // 8. co = tanh(sum + b_cat) -> bf16
    hipLaunchKernelGGL(co_reduce_kernel, dim3(512), dim3(256), 0, stream,
                       co_part, b_cat, co_hi);
    // 9. out = co @ W_out.T + b_out, waveGEMM: 3125 waves
    hipLaunchKernelGGL(out_wgemm, dim3(782), dim3(256), 0, stream,
                       co_hi, W_out, b_out, out);
}

// Round 6
// 178.574 us; speedup vs baseline: 1.6958x; 1.6958x over previous
//
#include <hip/hip_runtime.h>
#include <hip/hip_bf16.h>
#include <cstddef>

#define B_   128
#define L_   128
#define H_   1024
#define V_   50000
#define INDIM 1088   // H + 32 + 32

typedef short short8 __attribute__((ext_vector_type(8)));
typedef unsigned short ushort8 __attribute__((ext_vector_type(8)));
typedef unsigned short ushort4v __attribute__((ext_vector_type(4)));
typedef float f32x4 __attribute__((ext_vector_type(4)));

static __device__ __forceinline__ unsigned short f2bf(float f) {
    unsigned u = __builtin_bit_cast(unsigned, f);
    u = u + 0x7FFFu + ((u >> 16) & 1u);
    return (unsigned short)(u >> 16);
}
static __device__ __forceinline__ float bf2f(unsigned short h) {
    unsigned u = ((unsigned)h) << 16;
    return __builtin_bit_cast(float, u);
}
static __device__ __forceinline__ float sigm(float v) {
    return 1.f / (1.f + __expf(-v));
}

// packed f32x2 -> bf16x2 (RNE), gfx950 HW instruction
static __device__ __forceinline__ unsigned cvt_pk(float lo, float hi) {
    unsigned r;
    asm("v_cvt_pk_bf16_f32 %0, %1, %2" : "=v"(r) : "v"(lo), "v"(hi));
    return r;
}
static __device__ __forceinline__ short8 cvt8(float4 a, float4 b) {
    union { unsigned u[4]; short8 s; } r;
    r.u[0] = cvt_pk(a.x, a.y); r.u[1] = cvt_pk(a.z, a.w);
    r.u[2] = cvt_pk(b.x, b.y); r.u[3] = cvt_pk(b.z, b.w);
    return r.s;
}

// async global -> LDS, 16 B per lane (wave-uniform LDS base + lane*16)
static __device__ __forceinline__ void gload16(const float* g, float* l) {
    __builtin_amdgcn_global_load_lds(
        (const __attribute__((address_space(1))) unsigned*)g,
        (__attribute__((address_space(3))) unsigned*)l, 16, 0, 0);
}

#define MFMA(a, b, c) __builtin_amdgcn_mfma_f32_16x16x32_bf16((a), (b), (c), 0, 0, 0)

// ---------------------------------------------------------------------------
// prep: x = [emb|semb|nemb] and h = lh, both as bf16 hi/lo planes
// ---------------------------------------------------------------------------
__global__ __launch_bounds__(256) void prep_kernel(
    const int* __restrict__ seq, const int* __restrict__ c2n,
    const int* __restrict__ c2f, const float* __restrict__ emb,
    const float* __restrict__ semb, const float* __restrict__ nemb,
    const float* __restrict__ lh,
    unsigned short* __restrict__ x_hi, unsigned short* __restrict__ x_lo,
    unsigned short* __restrict__ h_hi, unsigned short* __restrict__ h_lo)
{
    const int b = blockIdx.x, t = threadIdx.x;
    const int idx = seq[b];
    for (int i = t; i < 528; i += 256) {
        float4 v;
        unsigned short *dh, *dl;
        int off;
        if (i < 272) {
            if (i < 256) {
                v = *(const float4*)&emb[(size_t)idx * H_ + i * 4];
            } else {
                const int j = i - 256;
                if (j < 8) v = *(const float4*)&semb[c2f[idx] * 32 + j * 4];
                else       v = *(const float4*)&nemb[c2n[idx] * 32 + (j - 8) * 4];
            }
            dh = x_hi + (size_t)b * INDIM; dl = x_lo + (size_t)b * INDIM; off = i * 4;
        } else {
            const int j = i - 272;
            v = *(const float4*)&lh[(size_t)b * H_ + j * 4];
            dh = h_hi + (size_t)b * H_; dl = h_lo + (size_t)b * H_; off = j * 4;
        }
        const float fv[4] = {v.x, v.y, v.z, v.w};
        ushort4v hh, ll;
#pragma unroll
        for (int e = 0; e < 4; e++) {
            hh[e] = f2bf(fv[e]);
            ll[e] = f2bf(fv[e] - bf2f(hh[e]));
        }
        *(ushort4v*)&dh[off] = hh;
        *(ushort4v*)&dl[off] = ll;
    }
}

// ---------------------------------------------------------------------------
// Streaming MFMA GEMM body (R4 structure, known-good).
// ---------------------------------------------------------------------------
template<bool WT, bool SPLIT, bool TANH>
static __device__ __forceinline__ void sgemm_body(
    const unsigned short* __restrict__ Ah, const unsigned short* __restrict__ Al, int lda,
    const float* __restrict__ W, int ldw,
    const float* __restrict__ bias,
    float* __restrict__ C, int ldc, size_t pstride,
    int N, int k_len0, int k_lenB)
{
    extern __shared__ char smem_raw[];
    typedef unsigned short RowT[72];
    RowT* As_h = (RowT*)(smem_raw);            // 128 rows * 144 B = 18432
    RowT* Ws_h = (RowT*)(smem_raw + 18432);    //  64 rows           9216
    RowT* As_l = (RowT*)(smem_raw + 27648);    // split only
    RowT* Ws_l = (RowT*)(smem_raw + 46080);    // split only

    const int t    = threadIdx.x;
    const int lane = t & 63;
    const int wv   = t >> 6;
    const int wr   = wv >> 1;
    const int wc   = wv & 1;
    const int n0   = blockIdx.x * 64;
    const int l15  = lane & 15;
    const int g    = lane >> 4;

    const int y     = blockIdx.y;
    const int k_off = (y == 0) ? 0 : k_len0 + (y - 1) * k_lenB;
    const int k_len = (y == 0) ? k_len0 : k_lenB;
    float* Cp = C + (size_t)y * pstride;

    const int ar = t >> 3;
    const int ac = (t & 7) * 8;
    const int wn = t >> 2, wq = t & 3;
    const int nk = t >> 4, nn4 = (t & 15) * 4;

    f32x4 acc[4][2];
#pragma unroll
    for (int i = 0; i < 4; i++)
#pragma unroll
        for (int j = 0; j < 2; j++) acc[i][j] = (f32x4){0.f, 0.f, 0.f, 0.f};

#define LOAD_A(K0, RA, RAL) do {                                               \
    _Pragma("unroll")                                                          \
    for (int i_ = 0; i_ < 4; i_++)                                             \
        RA[i_] = *(const ushort8*)&Ah[(size_t)(ar + i_ * 32) * lda + (K0) + ac]; \
    if constexpr (SPLIT) {                                                     \
        _Pragma("unroll")                                                      \
        for (int i_ = 0; i_ < 4; i_++)                                         \
            RAL[i_] = *(const ushort8*)&Al[(size_t)(ar + i_ * 32) * lda + (K0) + ac]; \
    }                                                                          \
} while (0)

#define LOAD_W(K0, RW) do {                                                    \
    if constexpr (WT) {                                                        \
        const bool ok_ = (n0 + wn) < N;                                        \
        const float* wb_ = W + (size_t)(n0 + wn) * ldw + (K0);                 \
        _Pragma("unroll")                                                      \
        for (int j_ = 0; j_ < 4; j_++)                                         \
            RW[j_] = ok_ ? *(const float4*)&wb_[j_ * 16 + wq * 4]              \
                         : make_float4(0.f, 0.f, 0.f, 0.f);                    \
    } else {                                                                   \
        _Pragma("unroll")                                                      \
        for (int j_ = 0; j_ < 4; j_++)                                         \
            RW[j_] = *(const float4*)&W[(size_t)((K0) + nk + j_ * 16) * ldw + n0 + nn4]; \
    }                                                                          \
} while (0)

#define STAGE_REGS(RA, RAL, RW) do {                                           \
    _Pragma("unroll")                                                          \
    for (int i_ = 0; i_ < 4; i_++) {                                           \
        *(ushort8*)&As_h[ar + i_ * 32][ac] = RA[i_];                           \
        if constexpr (SPLIT) *(ushort8*)&As_l[ar + i_ * 32][ac] = RAL[i_];     \
    }                                                                          \
    if constexpr (WT) {                                                        \
        _Pragma("unroll")                                                      \
        for (int j_ = 0; j_ < 4; j_++) {                                       \
            const float fv_[4] = {RW[j_].x, RW[j_].y, RW[j_].z, RW[j_].w};     \
            ushort4v hh_, ll_;                                                 \
            _Pragma("unroll")                                                  \
            for (int e_ = 0; e_ < 4; e_++) {                                   \
                hh_[e_] = f2bf(fv_[e_]);                                       \
                if constexpr (SPLIT) ll_[e_] = f2bf(fv_[e_] - bf2f(hh_[e_]));  \
            }                                                                  \
            *(ushort4v*)&Ws_h[wn][j_ * 16 + wq * 4] = hh_;                     \
            if constexpr (SPLIT) *(ushort4v*)&Ws_l[wn][j_ * 16 + wq * 4] = ll_; \
        }                                                                      \
    } else {                                                                   \
        _Pragma("unroll")                                                      \
        for (int j_ = 0; j_ < 4; j_++) {                                       \
            const float fv_[4] = {RW[j_].x, RW[j_].y, RW[j_].z, RW[j_].w};     \
            _Pragma("unroll")                                                  \
            for (int e_ = 0; e_ < 4; e_++) {                                   \
                const unsigned short hb_ = f2bf(fv_[e_]);                      \
                Ws_h[nn4 + e_][nk + j_ * 16] = hb_;                            \
                if constexpr (SPLIT)                                           \
                    Ws_l[nn4 + e_][nk + j_ * 16] = f2bf(fv_[e_] - bf2f(hb_));  \
            }                                                                  \
        }                                                                      \
    }                                                                          \
} while (0)

    const int k_end = k_off + k_len;

    ushort8 ra[4], ral[4], nra[4], nral[4];
    float4 rw0[4], rw1[4], rw2[4];

    LOAD_A(k_off, ra, ral);
    LOAD_W(k_off, rw0);
    if constexpr (!SPLIT) {
        if (k_off + 64 < k_end) LOAD_W(k_off + 64, rw1);
    }

    for (int k0 = k_off; k0 < k_end; k0 += 64) {
        const bool m1 = (k0 + 64) < k_end;
        const bool m2 = (k0 + 128) < k_end;
        if (m1) {
            LOAD_A(k0 + 64, nra, nral);
            if constexpr (SPLIT) LOAD_W(k0 + 64, rw1);
        }

        STAGE_REGS(ra, ral, rw0);
        __syncthreads();

        if constexpr (!SPLIT) {
            if (m2) LOAD_W(k0 + 128, rw2);
        }

#pragma unroll
        for (int ks = 0; ks < 2; ks++) {
            const int ko = ks * 32 + g * 8;
            short8 ah[4], bh[2];
#pragma unroll
            for (int mi = 0; mi < 4; mi++)
                ah[mi] = *(const short8*)&As_h[wr * 64 + mi * 16 + l15][ko];
#pragma unroll
            for (int ni = 0; ni < 2; ni++)
                bh[ni] = *(const short8*)&Ws_h[wc * 32 + ni * 16 + l15][ko];
            if constexpr (SPLIT) {
                short8 al[4], bl[2];
#pragma unroll
                for (int mi = 0; mi < 4; mi++)
                    al[mi] = *(const short8*)&As_l[wr * 64 + mi * 16 + l15][ko];
#pragma unroll
                for (int ni = 0; ni < 2; ni++)
                    bl[ni] = *(const short8*)&Ws_l[wc * 32 + ni * 16 + l15][ko];
#pragma unroll
                for (int mi = 0; mi < 4; mi++)
#pragma unroll
                    for (int ni = 0; ni < 2; ni++) {
                        acc[mi][ni] = MFMA(ah[mi], bh[ni], acc[mi][ni]);
                        acc[mi][ni] = MFMA(ah[mi], bl[ni], acc[mi][ni]);
                        acc[mi][ni] = MFMA(al[mi], bh[ni], acc[mi][ni]);
                    }
            } else {
#pragma unroll
                for (int mi = 0; mi < 4; mi++)
#pragma unroll
                    for (int ni = 0; ni < 2; ni++)
                        acc[mi][ni] = MFMA(ah[mi], bh[ni], acc[mi][ni]);
            }
        }
        __syncthreads();

        if (m1) {
#pragma unroll
            for (int i = 0; i < 4; i++) {
                ra[i] = nra[i];
                if constexpr (SPLIT) ral[i] = nral[i];
            }
#pragma unroll
            for (int j = 0; j < 4; j++) {
                rw0[j] = rw1[j];
                if constexpr (!SPLIT) rw1[j] = rw2[j];
            }
        }
    }
#undef LOAD_A
#undef LOAD_W
#undef STAGE_REGS

#pragma unroll
    for (int mi = 0; mi < 4; mi++) {
#pragma unroll
        for (int ni = 0; ni < 2; ni++) {
            const int col = n0 + wc * 32 + ni * 16 + l15;
            if (col < N) {
                const float bb = bias ? bias[col] : 0.f;
#pragma unroll
                for (int r = 0; r < 4; r++) {
                    const int row = wr * 64 + mi * 16 + g * 4 + r;
                    float v = acc[mi][ni][r] + bb;
                    if (TANH) v = tanhf(v);
                    Cp[(size_t)row * ldc + col] = v;
                }
            }
        }
    }
}

template<bool WT, bool SPLIT, bool TANH>
__global__ __launch_bounds__(256, 2) void sgemm(
    const unsigned short* __restrict__ Ah, const unsigned short* __restrict__ Al, int lda,
    const float* __restrict__ W, int ldw,
    const float* __restrict__ bias,
    float* __restrict__ C, int ldc, size_t pstride,
    int N, int k_len0, int k_lenB)
{
    sgemm_body<WT, SPLIT, TANH>(Ah, Al, lda, W, ldw, bias, C, ldc, pstride, N, k_len0, k_lenB);
}

// Merged gi+gh launch: blockIdx.z selects parameter set.
__global__ __launch_bounds__(256, 2) void gru_gemm(
    const unsigned short* __restrict__ x_hi, const unsigned short* __restrict__ x_lo,
    const float* __restrict__ W_ih,
    const unsigned short* __restrict__ h_hi, const unsigned short* __restrict__ h_lo,
    const float* __restrict__ W_hh,
    float* __restrict__ gi, float* __restrict__ gh)
{
    if (blockIdx.z == 0)
        sgemm_body<true, true, false>(x_hi, x_lo, INDIM, W_ih, INDIM, nullptr,
                                      gi, 3072, (size_t)128 * 3072, 3072, 320, 256);
    else
        sgemm_body<true, true, false>(h_hi, h_lo, H_, W_hh, H_, nullptr,
                                      gh, 3072, (size_t)128 * 3072, 3072, 256, 256);
}

// ---------------------------------------------------------------------------
// out = co @ W_out.T + b_out — 2-phase global_load_lds pipeline.
// W staged f32 direct-to-LDS (dbuf 2x16KB), counted vmcnt(4) + raw barriers
// (loads stay in flight across barriers; vmcnt(0) only on the peeled last
// iter). XOR-swizzled via pre-swizzled SOURCE (rule 21): LDS slot
// s=row*16+(col4^(row&7)) holds W[row][col4*4..+4); read applies same XOR ->
// 2-way bank aliasing (free). A (co_hi bf16, L2-resident) loads straight
// into fragment registers — no A staging, no stage-phase VALU.
// ---------------------------------------------------------------------------
__global__ __launch_bounds__(256, 4) void out_gemm2(
    const unsigned short* __restrict__ co_hi,   // [128][1024] bf16
    const float* __restrict__ W_out,            // [50000][1024] f32
    const float* __restrict__ b_out,
    float* __restrict__ C)                      // [128][50000] f32
{
    __shared__ float buf[2][4096];              // 2 x 16 KB
    const int t = threadIdx.x;
    const int lane = t & 63;
    const int wv = t >> 6;
    const int wr = wv >> 1, wc = wv & 1;
    const int l15 = lane & 15, g = lane >> 4;
    const int n0 = blockIdx.x * 64;

    // stage-source map (involution: read XOR == source XOR)
    const float* rowp[4];
    int colo[4];
#pragma unroll
    for (int r = 0; r < 4; r++) {
        const int s = r * 256 + t;          // 16B slot index in tile
        const int row = s >> 4;             // 0..63
        const int col4 = (s & 15) ^ (row & 7);
        const int grow = min(n0 + row, V_ - 1);
        rowp[r] = W_out + (size_t)grow * H_;
        colo[r] = col4 * 4;
    }

#define OSTAGE(CUR, K0) do {                                                  \
    _Pragma("unroll")                                                         \
    for (int r_ = 0; r_ < 4; r_++)                                            \
        gload16(rowp[r_] + (K0) + colo[r_], &buf[CUR][r_ * 1024 + t * 4]);    \
} while (0)

#define OLRD(CUR, ROW, C4) (*(const float4*)((const char*)(&buf[CUR][0]) +    \
    ((ROW) * 256 + ((((C4) ^ ((ROW) & 7))) << 4))))

    f32x4 acc[4][2];
#pragma unroll
    for (int i = 0; i < 4; i++)
#pragma unroll
        for (int j = 0; j < 2; j++) acc[i][j] = (f32x4){0.f, 0.f, 0.f, 0.f};

    OSTAGE(0, 0);
    OSTAGE(1, 64);

    for (int it = 0; it < 16; ++it) {
        const int cur = it & 1;
        const int k0 = it * 64;
        if (it < 15) asm volatile("s_waitcnt vmcnt(4)" ::: "memory");
        else         asm volatile("s_waitcnt vmcnt(0)" ::: "memory");
        __builtin_amdgcn_s_barrier();

#pragma unroll
        for (int ks = 0; ks < 2; ks++) {
            const int k = k0 + ks * 32 + g * 8;
            const int c4 = ks * 8 + g * 2;
            short8 bh[2];
#pragma unroll
            for (int ni = 0; ni < 2; ni++) {
                const int row = wc * 32 + ni * 16 + l15;
                float4 w0 = cur ? OLRD(1, row, c4)     : OLRD(0, row, c4);
                float4 w1 = cur ? OLRD(1, row, c4 + 1) : OLRD(0, row, c4 + 1);
                bh[ni] = cvt8(w0, w1);
            }
#pragma unroll
            for (int mi = 0; mi < 4; mi++) {
                const short8 ah = *(const short8*)&co_hi[(size_t)(wr * 64 + mi * 16 + l15) * H_ + k];
#pragma unroll
                for (int ni = 0; ni < 2; ni++)
                    acc[mi][ni] = MFMA(ah, bh[ni], acc[mi][ni]);
            }
        }
        asm volatile("s_waitcnt lgkmcnt(0)" ::: "memory");
        __builtin_amdgcn_sched_barrier(0);
        __builtin_amdgcn_s_barrier();
        if (it + 2 < 16) {
            if (cur) OSTAGE(1, k0 + 128);
            else     OSTAGE(0, k0 + 128);
        }
    }
#undef OSTAGE
#undef OLRD

#pragma unroll
    for (int mi = 0; mi < 4; mi++)
#pragma unroll
        for (int ni = 0; ni < 2; ni++) {
            const int col = n0 + wc * 32 + ni * 16 + l15;
            if (col < V_) {
                const float bb = b_out[col];
#pragma unroll
                for (int r = 0; r < 4; r++)
                    C[(size_t)(wr * 64 + mi * 16 + g * 4 + r) * V_ + col] = acc[mi][ni][r] + bb;
            }
        }
}

// ---------------------------------------------------------------------------
// GRU gates: sums 4 k-slice partials of gi/gh, adds biases, computes h.
// ---------------------------------------------------------------------------
__global__ __launch_bounds__(256) void gru_gates_kernel(
    const float* __restrict__ gi, const float* __restrict__ gh,
    const float* __restrict__ b_ih, const float* __restrict__ b_hh,
    const float* __restrict__ h_prev,
    float* __restrict__ hid_out,
    unsigned short* __restrict__ cat_hi, unsigned short* __restrict__ cat_lo)
{
    const int id = blockIdx.x * 256 + threadIdx.x;
    const int b = id >> 10, j = id & 1023;
    const size_t base = (size_t)b * 3072 + j;
    float ir = b_ih[j], iz = b_ih[1024 + j], in_ = b_ih[2048 + j];
    float hr = b_hh[j], hz = b_hh[1024 + j], hn = b_hh[2048 + j];
#pragma unroll
    for (int p = 0; p < 4; p++) {
        const float* gp = gi + (size_t)p * (128 * 3072);
        const float* hp = gh + (size_t)p * (128 * 3072);
        ir += gp[base]; iz += gp[base + 1024]; in_ += gp[base + 2048];
        hr += hp[base]; hz += hp[base + 1024]; hn += hp[base + 2048];
    }
    const float r = sigm(ir + hr);
    const float z = sigm(iz + hz);
    const float n = tanhf(in_ + r * hn);
    const float h = (1.f - z) * n + z * h_prev[id];
    hid_out[id] = h;
    const unsigned short hb = f2bf(h);
    cat_hi[(size_t)b * 2048 + j] = hb;
    cat_lo[(size_t)b * 2048 + j] = f2bf(h - bf2f(hb));
}

// ---------------------------------------------------------------------------
// energies (partial over 4 h-slices); 512 thr = 8 waves, 16 l each.
// ---------------------------------------------------------------------------
__global__ __launch_bounds__(512) void energy_partial_kernel(
    const float* __restrict__ qp, const float* __restrict__ enc,
    float* __restrict__ epart)
{
    const int s = blockIdx.x, b = blockIdx.y;
    const int t = threadIdx.x, lane = t & 63, wv = t >> 6;
    __shared__ float q_s[256];
    if (t < 256) {
        const size_t o = (size_t)b * H_ + s * 256 + t;
        q_s[t] = qp[o] + qp[o + 131072] + qp[o + 262144] + qp[o + 393216];
    }
    __syncthreads();
    const float4 qv = *(const float4*)&q_s[lane * 4];
    const float* encb = enc + (size_t)b * H_ + s * 256;
    for (int l0 = 0; l0 < 16; l0++) {
        const int l = wv * 16 + l0;
        float4 ev = *(const float4*)&encb[(size_t)l * (B_ * H_) + lane * 4];
        float p = ev.x * qv.x + ev.y * qv.y + ev.z * qv.z + ev.w * qv.w;
#pragma unroll
        for (int off = 32; off > 0; off >>= 1) p += __shfl_xor(p, off);
        if (lane == 0) epart[((size_t)b * 128 + l) * 4 + s] = p;
    }
}

// ---------------------------------------------------------------------------
// Fused softmax + context; s==0 writes attnw.
// ---------------------------------------------------------------------------
__global__ __launch_bounds__(256) void context_softmax_kernel(
    const float* __restrict__ epart, const float* __restrict__ enc,
    unsigned short* __restrict__ cat_hi, float* __restrict__ attnw)
{
    const int s = blockIdx.x, b = blockIdx.y, t = threadIdx.x;
    const int lane = t & 63, wv = t >> 6;
    __shared__ float w_s[128];
    __shared__ float red[4];

    float e = -INFINITY;
    if (t < 128) {
        float4 pe = *(const float4*)&epart[((size_t)b * 128 + t) * 4];
        e = pe.x + pe.y + pe.z + pe.w;
    }
    float mx = e;
#pragma unroll
    for (int off = 32; off > 0; off >>= 1) mx = fmaxf(mx, __shfl_xor(mx, off));
    if (lane == 0) red[wv] = mx;
    __syncthreads();
    const float gm = fmaxf(fmaxf(red[0], red[1]), fmaxf(red[2], red[3]));
    __syncthreads();
    float ex = (t < 128) ? __expf(e - gm) : 0.f;
    float sm = ex;
#pragma unroll
    for (int off = 32; off > 0; off >>= 1) sm += __shfl_xor(sm, off);
    if (lane == 0) red[wv] = sm;
    __syncthreads();
    const float gs = red[0] + red[1] + red[2] + red[3];
    if (t < 128) {
        const float w = ex / gs;
        w_s[t] = w;
        if (s == 0) attnw[(size_t)b * L_ + t] = w;
    }
    __syncthreads();

    const int h = s * 256 + t;
    const float* encb = enc + (size_t)b * H_ + h;
    float c = 0.f;
#pragma unroll 4
    for (int l = 0; l < 128; l++)
        c += w_s[l] * encb[(size_t)l * (B_ * H_)];
    cat_hi[(size_t)b * 2048 + 1024 + h] = f2bf(c);
}

// co = tanh(sum of 4 partials + b_cat) -> bf16
__global__ __launch_bounds__(256) void co_reduce_kernel(
    const float* __restrict__ co_part, const float* __restrict__ b_cat,
    unsigned short* __restrict__ co_hi)
{
    const int id = blockIdx.x * 256 + threadIdx.x;
    const int j = id & 1023;
    float s = b_cat[j];
#pragma unroll
    for (int p = 0; p < 4; p++) s += co_part[(size_t)p * 131072 + id];
    co_hi[id] = f2bf(tanhf(s));
}

// ---------------------------------------------------------------------------
extern "C" void kernel_launch(void* const* d_in, const int* in_sizes, int n_in,
                              void* d_out, int out_size, void* d_ws, size_t ws_size,
                              hipStream_t stream)
{
    const int*   seq    = (const int*)  d_in[0];
    const float* lh     = (const float*)d_in[1];
    const float* enc    = (const float*)d_in[2];
    const int*   c2n    = (const int*)  d_in[3];
    const int*   c2f    = (const int*)  d_in[4];
    const float* emb    = (const float*)d_in[5];
    const float* semb   = (const float*)d_in[6];
    const float* nemb   = (const float*)d_in[7];
    const float* W_ih   = (const float*)d_in[8];
    const float* W_hh   = (const float*)d_in[9];
    const float* b_ih   = (const float*)d_in[10];
    const float* b_hh   = (const float*)d_in[11];
    const float* W_attn = (const float*)d_in[12];
    // d_in[13] = b_attn: dropped (softmax shift-invariant, exact)
    const float* W_cat  = (const float*)d_in[14];
    const float* b_cat  = (const float*)d_in[15];
    const float* W_out  = (const float*)d_in[16];
    const float* b_out  = (const float*)d_in[17];

    float* out    = (float*)d_out;
    float* hidden = out + (size_t)B_ * V_;
    float* attnw  = hidden + (size_t)B_ * H_;

    // ---- workspace layout ----
    unsigned short* x_hi   = (unsigned short*)d_ws;            // 128*1088
    unsigned short* x_lo   = x_hi   + (size_t)128 * INDIM;
    unsigned short* h_hi   = x_lo   + (size_t)128 * INDIM;     // 128*1024
    unsigned short* h_lo   = h_hi   + (size_t)128 * 1024;
    unsigned short* cat_hi = h_lo   + (size_t)128 * 1024;      // 128*2048
    unsigned short* cat_lo = cat_hi + (size_t)128 * 2048;
    unsigned short* co_hi  = cat_lo + (size_t)128 * 2048;      // 128*1024
    float* fbase   = (float*)(co_hi + (size_t)128 * 1024);
    float* gi_part = fbase;                                    // 4*128*3072
    float* gh_part = gi_part + (size_t)4 * 128 * 3072;         // 4*128*3072
    // aliases (gi/gh dead after gates):
    float* q_part  = fbase;                                    // 4*128*1024
    float* co_part = q_part + (size_t)4 * 128 * 1024;          // 4*128*1024
    float* epart   = co_part + (size_t)4 * 128 * 1024;         // 128*128*4

    const int SMEM_SPLIT = 55296;
    const int SMEM_PLAIN = 27648;

    // 1. prep: x, h bf16 hi/lo planes
    hipLaunchKernelGGL(prep_kernel, dim3(B_), dim3(256), 0, stream,
                       seq, c2n, c2f, emb, semb, nemb, lh, x_hi, x_lo, h_hi, h_lo);
    // 2+3. gi & gh partials in one dispatch (z selects)
    hipLaunchKernelGGL(gru_gemm, dim3(48, 4, 2), dim3(256), SMEM_SPLIT, stream,
                       x_hi, x_lo, W_ih, h_hi, h_lo, W_hh, gi_part, gh_part);
    // 4. gates -> hidden + cat planes
    hipLaunchKernelGGL(gru_gates_kernel, dim3(512), dim3(256), 0, stream,
                       gi_part, gh_part, b_ih, b_hh, lh, hidden, cat_hi, cat_lo);
    // 5. q partials = h @ W_attn (NT, split): K=1024 -> 4 x 256
    hipLaunchKernelGGL((sgemm<false, true, false>), dim3(16, 4), dim3(256), SMEM_SPLIT, stream,
                       cat_hi, cat_lo, 2048, W_attn, H_, (const float*)nullptr,
                       q_part, H_, (size_t)128 * 1024, H_, 256, 256);
    // 6. energies
    hipLaunchKernelGGL(energy_partial_kernel, dim3(4, 128), dim3(512), 0, stream,
                       q_part, enc, epart);
    // 7. softmax + context fused
    hipLaunchKernelGGL(context_softmax_kernel, dim3(4, 128), dim3(256), 0, stream,
                       epart, enc, cat_hi, attnw);
    // 8. co partials = cat @ W_cat.T: K=2048 -> 4 x 512
    hipLaunchKernelGGL((sgemm<true, false, false>), dim3(16, 4), dim3(256), SMEM_PLAIN, stream,
                       cat_hi, cat_hi, 2048, W_cat, 2048, (const float*)nullptr,
                       co_part, H_, (size_t)128 * 1024, H_, 512, 512);
    // 9. co = tanh(sum + b_cat) -> bf16
    hipLaunchKernelGGL(co_reduce_kernel, dim3(512), dim3(256), 0, stream,
                       co_part, b_cat, co_hi);
    // 10. out = co @ W_out.T + b_out — 2-phase gload_lds pipeline
    hipLaunchKernelGGL(out_gemm2, dim3((V_ + 63) / 64), dim3(256), 0, stream,
                       co_hi, W_out, b_out, out);
}

// Round 7
// 169.849 us; speedup vs baseline: 1.7829x; 1.0514x over previous
//
#include <hip/hip_runtime.h>
#include <hip/hip_bf16.h>
#include <cstddef>

#define B_   128
#define L_   128
#define H_   1024
#define V_   50000
#define INDIM 1088   // H + 32 + 32

typedef short short8 __attribute__((ext_vector_type(8)));
typedef unsigned short ushort8 __attribute__((ext_vector_type(8)));
typedef unsigned short ushort4v __attribute__((ext_vector_type(4)));
typedef float f32x4 __attribute__((ext_vector_type(4)));

static __device__ __forceinline__ unsigned short f2bf(float f) {
    unsigned u = __builtin_bit_cast(unsigned, f);
    u = u + 0x7FFFu + ((u >> 16) & 1u);
    return (unsigned short)(u >> 16);
}
static __device__ __forceinline__ float bf2f(unsigned short h) {
    unsigned u = ((unsigned)h) << 16;
    return __builtin_bit_cast(float, u);
}
static __device__ __forceinline__ float sigm(float v) {
    return 1.f / (1.f + __expf(-v));
}

// packed f32x2 -> bf16x2 (RNE), gfx950 HW instruction
static __device__ __forceinline__ unsigned cvt_pk(float lo, float hi) {
    unsigned r;
    asm("v_cvt_pk_bf16_f32 %0, %1, %2" : "=v"(r) : "v"(lo), "v"(hi));
    return r;
}
static __device__ __forceinline__ short8 cvt8(float4 a, float4 b) {
    union { unsigned u[4]; short8 s; } r;
    r.u[0] = cvt_pk(a.x, a.y); r.u[1] = cvt_pk(a.z, a.w);
    r.u[2] = cvt_pk(b.x, b.y); r.u[3] = cvt_pk(b.z, b.w);
    return r.s;
}
static __device__ __forceinline__ ushort4v cvt4(float4 v) {
    const unsigned p01 = cvt_pk(v.x, v.y);
    const unsigned p23 = cvt_pk(v.z, v.w);
    ushort4v r;
    r[0] = (unsigned short)p01; r[1] = (unsigned short)(p01 >> 16);
    r[2] = (unsigned short)p23; r[3] = (unsigned short)(p23 >> 16);
    return r;
}
static __device__ __forceinline__ void cvt4_split(float4 v, ushort4v& hh, ushort4v& ll) {
    const unsigned p01 = cvt_pk(v.x, v.y);
    const unsigned p23 = cvt_pk(v.z, v.w);
    hh[0] = (unsigned short)p01; hh[1] = (unsigned short)(p01 >> 16);
    hh[2] = (unsigned short)p23; hh[3] = (unsigned short)(p23 >> 16);
    const float r0 = v.x - __builtin_bit_cast(float, p01 << 16);
    const float r1 = v.y - __builtin_bit_cast(float, p01 & 0xFFFF0000u);
    const float r2 = v.z - __builtin_bit_cast(float, p23 << 16);
    const float r3 = v.w - __builtin_bit_cast(float, p23 & 0xFFFF0000u);
    const unsigned q01 = cvt_pk(r0, r1);
    const unsigned q23 = cvt_pk(r2, r3);
    ll[0] = (unsigned short)q01; ll[1] = (unsigned short)(q01 >> 16);
    ll[2] = (unsigned short)q23; ll[3] = (unsigned short)(q23 >> 16);
}

// async global -> LDS, 16 B per lane (wave-uniform LDS base + lane*16)
static __device__ __forceinline__ void gload16(const float* g, float* l) {
    __builtin_amdgcn_global_load_lds(
        (const __attribute__((address_space(1))) unsigned*)g,
        (__attribute__((address_space(3))) unsigned*)l, 16, 0, 0);
}

#define MFMA(a, b, c) __builtin_amdgcn_mfma_f32_16x16x32_bf16((a), (b), (c), 0, 0, 0)

// ---------------------------------------------------------------------------
// prep: x = [emb|semb|nemb] and h = lh, both as bf16 hi/lo planes
// ---------------------------------------------------------------------------
__global__ __launch_bounds__(256) void prep_kernel(
    const int* __restrict__ seq, const int* __restrict__ c2n,
    const int* __restrict__ c2f, const float* __restrict__ emb,
    const float* __restrict__ semb, const float* __restrict__ nemb,
    const float* __restrict__ lh,
    unsigned short* __restrict__ x_hi, unsigned short* __restrict__ x_lo,
    unsigned short* __restrict__ h_hi, unsigned short* __restrict__ h_lo)
{
    const int b = blockIdx.x, t = threadIdx.x;
    const int idx = seq[b];
    for (int i = t; i < 528; i += 256) {
        float4 v;
        unsigned short *dh, *dl;
        int off;
        if (i < 272) {
            if (i < 256) {
                v = *(const float4*)&emb[(size_t)idx * H_ + i * 4];
            } else {
                const int j = i - 256;
                if (j < 8) v = *(const float4*)&semb[c2f[idx] * 32 + j * 4];
                else       v = *(const float4*)&nemb[c2n[idx] * 32 + (j - 8) * 4];
            }
            dh = x_hi + (size_t)b * INDIM; dl = x_lo + (size_t)b * INDIM; off = i * 4;
        } else {
            const int j = i - 272;
            v = *(const float4*)&lh[(size_t)b * H_ + j * 4];
            dh = h_hi + (size_t)b * H_; dl = h_lo + (size_t)b * H_; off = j * 4;
        }
        ushort4v hh, ll;
        cvt4_split(v, hh, ll);
        *(ushort4v*)&dh[off] = hh;
        *(ushort4v*)&dl[off] = ll;
    }
}

// ---------------------------------------------------------------------------
// Streaming MFMA GEMM body (R4 structure; staging cvt now via v_cvt_pk).
// ---------------------------------------------------------------------------
template<bool WT, bool SPLIT, bool TANH>
static __device__ __forceinline__ void sgemm_body(
    const unsigned short* __restrict__ Ah, const unsigned short* __restrict__ Al, int lda,
    const float* __restrict__ W, int ldw,
    const float* __restrict__ bias,
    float* __restrict__ C, int ldc, size_t pstride,
    int N, int k_len0, int k_lenB)
{
    extern __shared__ char smem_raw[];
    typedef unsigned short RowT[72];
    RowT* As_h = (RowT*)(smem_raw);            // 128 rows * 144 B = 18432
    RowT* Ws_h = (RowT*)(smem_raw + 18432);    //  64 rows           9216
    RowT* As_l = (RowT*)(smem_raw + 27648);    // split only
    RowT* Ws_l = (RowT*)(smem_raw + 46080);    // split only

    const int t    = threadIdx.x;
    const int lane = t & 63;
    const int wv   = t >> 6;
    const int wr   = wv >> 1;
    const int wc   = wv & 1;
    const int n0   = blockIdx.x * 64;
    const int l15  = lane & 15;
    const int g    = lane >> 4;

    const int y     = blockIdx.y;
    const int k_off = (y == 0) ? 0 : k_len0 + (y - 1) * k_lenB;
    const int k_len = (y == 0) ? k_len0 : k_lenB;
    float* Cp = C + (size_t)y * pstride;

    const int ar = t >> 3;
    const int ac = (t & 7) * 8;
    const int wn = t >> 2, wq = t & 3;
    const int nk = t >> 4, nn4 = (t & 15) * 4;

    f32x4 acc[4][2];
#pragma unroll
    for (int i = 0; i < 4; i++)
#pragma unroll
        for (int j = 0; j < 2; j++) acc[i][j] = (f32x4){0.f, 0.f, 0.f, 0.f};

#define LOAD_A(K0, RA, RAL) do {                                               \
    _Pragma("unroll")                                                          \
    for (int i_ = 0; i_ < 4; i_++)                                             \
        RA[i_] = *(const ushort8*)&Ah[(size_t)(ar + i_ * 32) * lda + (K0) + ac]; \
    if constexpr (SPLIT) {                                                     \
        _Pragma("unroll")                                                      \
        for (int i_ = 0; i_ < 4; i_++)                                         \
            RAL[i_] = *(const ushort8*)&Al[(size_t)(ar + i_ * 32) * lda + (K0) + ac]; \
    }                                                                          \
} while (0)

#define LOAD_W(K0, RW) do {                                                    \
    if constexpr (WT) {                                                        \
        const bool ok_ = (n0 + wn) < N;                                        \
        const float* wb_ = W + (size_t)(n0 + wn) * ldw + (K0);                 \
        _Pragma("unroll")                                                      \
        for (int j_ = 0; j_ < 4; j_++)                                         \
            RW[j_] = ok_ ? *(const float4*)&wb_[j_ * 16 + wq * 4]              \
                         : make_float4(0.f, 0.f, 0.f, 0.f);                    \
    } else {                                                                   \
        _Pragma("unroll")                                                      \
        for (int j_ = 0; j_ < 4; j_++)                                         \
            RW[j_] = *(const float4*)&W[(size_t)((K0) + nk + j_ * 16) * ldw + n0 + nn4]; \
    }                                                                          \
} while (0)

#define STAGE_REGS(RA, RAL, RW) do {                                           \
    _Pragma("unroll")                                                          \
    for (int i_ = 0; i_ < 4; i_++) {                                           \
        *(ushort8*)&As_h[ar + i_ * 32][ac] = RA[i_];                           \
        if constexpr (SPLIT) *(ushort8*)&As_l[ar + i_ * 32][ac] = RAL[i_];     \
    }                                                                          \
    if constexpr (WT) {                                                        \
        _Pragma("unroll")                                                      \
        for (int j_ = 0; j_ < 4; j_++) {                                       \
            ushort4v hh_, ll_;                                                 \
            if constexpr (SPLIT) cvt4_split(RW[j_], hh_, ll_);                 \
            else                 hh_ = cvt4(RW[j_]);                           \
            *(ushort4v*)&Ws_h[wn][j_ * 16 + wq * 4] = hh_;                     \
            if constexpr (SPLIT) *(ushort4v*)&Ws_l[wn][j_ * 16 + wq * 4] = ll_; \
        }                                                                      \
    } else {                                                                   \
        _Pragma("unroll")                                                      \
        for (int j_ = 0; j_ < 4; j_++) {                                       \
            ushort4v hh_, ll_;                                                 \
            if constexpr (SPLIT) cvt4_split(RW[j_], hh_, ll_);                 \
            else                 hh_ = cvt4(RW[j_]);                           \
            _Pragma("unroll")                                                  \
            for (int e_ = 0; e_ < 4; e_++) {                                   \
                Ws_h[nn4 + e_][nk + j_ * 16] = hh_[e_];                        \
                if constexpr (SPLIT) Ws_l[nn4 + e_][nk + j_ * 16] = ll_[e_];   \
            }                                                                  \
        }                                                                      \
    }                                                                          \
} while (0)

    const int k_end = k_off + k_len;

    ushort8 ra[4], ral[4], nra[4], nral[4];
    float4 rw0[4], rw1[4], rw2[4];

    LOAD_A(k_off, ra, ral);
    LOAD_W(k_off, rw0);
    if constexpr (!SPLIT) {
        if (k_off + 64 < k_end) LOAD_W(k_off + 64, rw1);
    }

    for (int k0 = k_off; k0 < k_end; k0 += 64) {
        const bool m1 = (k0 + 64) < k_end;
        const bool m2 = (k0 + 128) < k_end;
        if (m1) {
            LOAD_A(k0 + 64, nra, nral);
            if constexpr (SPLIT) LOAD_W(k0 + 64, rw1);
        }

        STAGE_REGS(ra, ral, rw0);
        __syncthreads();

        if constexpr (!SPLIT) {
            if (m2) LOAD_W(k0 + 128, rw2);
        }

#pragma unroll
        for (int ks = 0; ks < 2; ks++) {
            const int ko = ks * 32 + g * 8;
            short8 ah[4], bh[2];
#pragma unroll
            for (int mi = 0; mi < 4; mi++)
                ah[mi] = *(const short8*)&As_h[wr * 64 + mi * 16 + l15][ko];
#pragma unroll
            for (int ni = 0; ni < 2; ni++)
                bh[ni] = *(const short8*)&Ws_h[wc * 32 + ni * 16 + l15][ko];
            if constexpr (SPLIT) {
                short8 al[4], bl[2];
#pragma unroll
                for (int mi = 0; mi < 4; mi++)
                    al[mi] = *(const short8*)&As_l[wr * 64 + mi * 16 + l15][ko];
#pragma unroll
                for (int ni = 0; ni < 2; ni++)
                    bl[ni] = *(const short8*)&Ws_l[wc * 32 + ni * 16 + l15][ko];
#pragma unroll
                for (int mi = 0; mi < 4; mi++)
#pragma unroll
                    for (int ni = 0; ni < 2; ni++) {
                        acc[mi][ni] = MFMA(ah[mi], bh[ni], acc[mi][ni]);
                        acc[mi][ni] = MFMA(ah[mi], bl[ni], acc[mi][ni]);
                        acc[mi][ni] = MFMA(al[mi], bh[ni], acc[mi][ni]);
                    }
            } else {
#pragma unroll
                for (int mi = 0; mi < 4; mi++)
#pragma unroll
                    for (int ni = 0; ni < 2; ni++)
                        acc[mi][ni] = MFMA(ah[mi], bh[ni], acc[mi][ni]);
            }
        }
        __syncthreads();

        if (m1) {
#pragma unroll
            for (int i = 0; i < 4; i++) {
                ra[i] = nra[i];
                if constexpr (SPLIT) ral[i] = nral[i];
            }
#pragma unroll
            for (int j = 0; j < 4; j++) {
                rw0[j] = rw1[j];
                if constexpr (!SPLIT) rw1[j] = rw2[j];
            }
        }
    }
#undef LOAD_A
#undef LOAD_W
#undef STAGE_REGS

#pragma unroll
    for (int mi = 0; mi < 4; mi++) {
#pragma unroll
        for (int ni = 0; ni < 2; ni++) {
            const int col = n0 + wc * 32 + ni * 16 + l15;
            if (col < N) {
                const float bb = bias ? bias[col] : 0.f;
#pragma unroll
                for (int r = 0; r < 4; r++) {
                    const int row = wr * 64 + mi * 16 + g * 4 + r;
                    float v = acc[mi][ni][r] + bb;
                    if (TANH) v = tanhf(v);
                    Cp[(size_t)row * ldc + col] = v;
                }
            }
        }
    }
}

template<bool WT, bool SPLIT, bool TANH>
__global__ __launch_bounds__(256, 2) void sgemm(
    const unsigned short* __restrict__ Ah, const unsigned short* __restrict__ Al, int lda,
    const float* __restrict__ W, int ldw,
    const float* __restrict__ bias,
    float* __restrict__ C, int ldc, size_t pstride,
    int N, int k_len0, int k_lenB)
{
    sgemm_body<WT, SPLIT, TANH>(Ah, Al, lda, W, ldw, bias, C, ldc, pstride, N, k_len0, k_lenB);
}

// Merged gi+gh launch: blockIdx.z selects parameter set.
__global__ __launch_bounds__(256, 2) void gru_gemm(
    const unsigned short* __restrict__ x_hi, const unsigned short* __restrict__ x_lo,
    const float* __restrict__ W_ih,
    const unsigned short* __restrict__ h_hi, const unsigned short* __restrict__ h_lo,
    const float* __restrict__ W_hh,
    float* __restrict__ gi, float* __restrict__ gh)
{
    if (blockIdx.z == 0)
        sgemm_body<true, true, false>(x_hi, x_lo, INDIM, W_ih, INDIM, nullptr,
                                      gi, 3072, (size_t)128 * 3072, 3072, 320, 256);
    else
        sgemm_body<true, true, false>(h_hi, h_lo, H_, W_hh, H_, nullptr,
                                      gh, 3072, (size_t)128 * 3072, 3072, 256, 256);
}

// ---------------------------------------------------------------------------
// out = co @ W_out.T + b_out — corrected async pipeline.
// Issue order per iter (oldest->newest): W(it) LDS-stage, A(it) reg loads,
// W(it+1) LDS-stage  =>  s_waitcnt vmcnt(4) retires exactly {W(it), A(it)}
// and keeps W(it+1) in flight across both barriers. Compute phase is pure
// {ds_read, MFMA} — no VMEM ops, so nothing forces a drain (fixes R6 bug:
// in-phase A global loads made every compiler wait an effective vmcnt(0)).
// A regs double-buffered (named sets, x2 unroll, static indexing).
// W LDS XOR-swizzled via pre-swizzled source (validated R6).
// ---------------------------------------------------------------------------
__global__ __launch_bounds__(256, 2) void out_gemm3(
    const unsigned short* __restrict__ co_hi,   // [128][1024] bf16
    const float* __restrict__ W_out,            // [50000][1024] f32
    const float* __restrict__ b_out,
    float* __restrict__ C)                      // [128][50000] f32
{
    __shared__ float buf[2][4096];              // 2 x 16 KB
    const int t = threadIdx.x;
    const int lane = t & 63;
    const int wv = t >> 6;
    const int wr = wv >> 1, wc = wv & 1;
    const int l15 = lane & 15, g = lane >> 4;
    const int n0 = blockIdx.x * 64;

    // stage-source map (involution: read XOR == source XOR)
    const float* rowp[4];
    int colo[4];
#pragma unroll
    for (int r = 0; r < 4; r++) {
        const int s = r * 256 + t;          // 16B slot index in tile
        const int row = s >> 4;             // 0..63
        const int col4 = (s & 15) ^ (row & 7);
        const int grow = min(n0 + row, V_ - 1);
        rowp[r] = W_out + (size_t)grow * H_;
        colo[r] = col4 * 4;
    }
    const unsigned short* abase = co_hi + (size_t)(wr * 64 + l15) * H_ + g * 8;

#define OSTAGE(CUR, K0) do {                                                  \
    _Pragma("unroll")                                                         \
    for (int r_ = 0; r_ < 4; r_++)                                            \
        gload16(rowp[r_] + (K0) + colo[r_], &buf[CUR][r_ * 1024 + t * 4]);    \
} while (0)

#define OLRD(CUR, ROW, C4) (*(const float4*)((const char*)(&buf[CUR][0]) +    \
    ((ROW) * 256 + ((((C4) ^ ((ROW) & 7))) << 4))))

#define LOAD_AF(DST, K0) do {                                                 \
    _Pragma("unroll")                                                         \
    for (int mi_ = 0; mi_ < 4; mi_++)                                         \
        _Pragma("unroll")                                                     \
        for (int ks_ = 0; ks_ < 2; ks_++)                                     \
            DST[mi_][ks_] = *(const short8*)&abase[(size_t)(mi_ * 16) * H_ + (K0) + ks_ * 32]; \
} while (0)

    f32x4 acc[4][2];
#pragma unroll
    for (int i = 0; i < 4; i++)
#pragma unroll
        for (int j = 0; j < 2; j++) acc[i][j] = (f32x4){0.f, 0.f, 0.f, 0.f};

    short8 aA[4][2], aB[4][2];

    // prologue — order matters: W0, A0, W1
    OSTAGE(0, 0);
    LOAD_AF(aA, 0);
    OSTAGE(1, 64);

#define ITER(ITX, CURLIT, ACUR, ANXT) do {                                    \
    const int it_ = (ITX);                                                    \
    const int k0_ = it_ * 64;                                                 \
    if (it_ < 15) asm volatile("s_waitcnt vmcnt(4)" ::: "memory");            \
    else          asm volatile("s_waitcnt vmcnt(0)" ::: "memory");            \
    __builtin_amdgcn_s_barrier();                                             \
    _Pragma("unroll")                                                         \
    for (int ks = 0; ks < 2; ks++) {                                          \
        const int c4 = ks * 8 + g * 2;                                        \
        short8 bh[2];                                                         \
        _Pragma("unroll")                                                     \
        for (int ni = 0; ni < 2; ni++) {                                      \
            const int row = wc * 32 + ni * 16 + l15;                          \
            float4 w0 = OLRD(CURLIT, row, c4);                                \
            float4 w1 = OLRD(CURLIT, row, c4 + 1);                            \
            bh[ni] = cvt8(w0, w1);                                            \
        }                                                                     \
        _Pragma("unroll")                                                     \
        for (int mi = 0; mi < 4; mi++)                                        \
            _Pragma("unroll")                                                  \
            for (int ni = 0; ni < 2; ni++)                                    \
                acc[mi][ni] = MFMA(ACUR[mi][ks], bh[ni], acc[mi][ni]);        \
    }                                                                         \
    if (it_ + 1 < 16) LOAD_AF(ANXT, k0_ + 64);                                \
    asm volatile("s_waitcnt lgkmcnt(0)" ::: "memory");                        \
    __builtin_amdgcn_sched_barrier(0);                                        \
    __builtin_amdgcn_s_barrier();                                             \
    if (it_ + 2 < 16) OSTAGE(CURLIT, k0_ + 128);                              \
} while (0)

    for (int it = 0; it < 16; it += 2) {
        ITER(it,     0, aA, aB);
        ITER(it + 1, 1, aB, aA);
    }
#undef ITER
#undef OSTAGE
#undef OLRD
#undef LOAD_AF

#pragma unroll
    for (int mi = 0; mi < 4; mi++)
#pragma unroll
        for (int ni = 0; ni < 2; ni++) {
            const int col = n0 + wc * 32 + ni * 16 + l15;
            if (col < V_) {
                const float bb = b_out[col];
#pragma unroll
                for (int r = 0; r < 4; r++)
                    C[(size_t)(wr * 64 + mi * 16 + g * 4 + r) * V_ + col] = acc[mi][ni][r] + bb;
            }
        }
}

// ---------------------------------------------------------------------------
// GRU gates: sums 4 k-slice partials of gi/gh, adds biases, computes h.
// ---------------------------------------------------------------------------
__global__ __launch_bounds__(256) void gru_gates_kernel(
    const float* __restrict__ gi, const float* __restrict__ gh,
    const float* __restrict__ b_ih, const float* __restrict__ b_hh,
    const float* __restrict__ h_prev,
    float* __restrict__ hid_out,
    unsigned short* __restrict__ cat_hi, unsigned short* __restrict__ cat_lo)
{
    const int id = blockIdx.x * 256 + threadIdx.x;
    const int b = id >> 10, j = id & 1023;
    const size_t base = (size_t)b * 3072 + j;
    float ir = b_ih[j], iz = b_ih[1024 + j], in_ = b_ih[2048 + j];
    float hr = b_hh[j], hz = b_hh[1024 + j], hn = b_hh[2048 + j];
#pragma unroll
    for (int p = 0; p < 4; p++) {
        const float* gp = gi + (size_t)p * (128 * 3072);
        const float* hp = gh + (size_t)p * (128 * 3072);
        ir += gp[base]; iz += gp[base + 1024]; in_ += gp[base + 2048];
        hr += hp[base]; hz += hp[base + 1024]; hn += hp[base + 2048];
    }
    const float r = sigm(ir + hr);
    const float z = sigm(iz + hz);
    const float n = tanhf(in_ + r * hn);
    const float h = (1.f - z) * n + z * h_prev[id];
    hid_out[id] = h;
    const unsigned short hb = f2bf(h);
    cat_hi[(size_t)b * 2048 + j] = hb;
    cat_lo[(size_t)b * 2048 + j] = f2bf(h - bf2f(hb));
}

// ---------------------------------------------------------------------------
// energies (partial over 4 h-slices); 512 thr = 8 waves, 16 l each.
// ---------------------------------------------------------------------------
__global__ __launch_bounds__(512) void energy_partial_kernel(
    const float* __restrict__ qp, const float* __restrict__ enc,
    float* __restrict__ epart)
{
    const int s = blockIdx.x, b = blockIdx.y;
    const int t = threadIdx.x, lane = t & 63, wv = t >> 6;
    __shared__ float q_s[256];
    if (t < 256) {
        const size_t o = (size_t)b * H_ + s * 256 + t;
        q_s[t] = qp[o] + qp[o + 131072] + qp[o + 262144] + qp[o + 393216];
    }
    __syncthreads();
    const float4 qv = *(const float4*)&q_s[lane * 4];
    const float* encb = enc + (size_t)b * H_ + s * 256;
    for (int l0 = 0; l0 < 16; l0++) {
        const int l = wv * 16 + l0;
        float4 ev = *(const float4*)&encb[(size_t)l * (B_ * H_) + lane * 4];
        float p = ev.x * qv.x + ev.y * qv.y + ev.z * qv.z + ev.w * qv.w;
#pragma unroll
        for (int off = 32; off > 0; off >>= 1) p += __shfl_xor(p, off);
        if (lane == 0) epart[((size_t)b * 128 + l) * 4 + s] = p;
    }
}

// ---------------------------------------------------------------------------
// Fused softmax + context; s==0 writes attnw.
// ---------------------------------------------------------------------------
__global__ __launch_bounds__(256) void context_softmax_kernel(
    const float* __restrict__ epart, const float* __restrict__ enc,
    unsigned short* __restrict__ cat_hi, float* __restrict__ attnw)
{
    const int s = blockIdx.x, b = blockIdx.y, t = threadIdx.x;
    const int lane = t & 63, wv = t >> 6;
    __shared__ float w_s[128];
    __shared__ float red[4];

    float e = -INFINITY;
    if (t < 128) {
        float4 pe = *(const float4*)&epart[((size_t)b * 128 + t) * 4];
        e = pe.x + pe.y + pe.z + pe.w;
    }
    float mx = e;
#pragma unroll
    for (int off = 32; off > 0; off >>= 1) mx = fmaxf(mx, __shfl_xor(mx, off));
    if (lane == 0) red[wv] = mx;
    __syncthreads();
    const float gm = fmaxf(fmaxf(red[0], red[1]), fmaxf(red[2], red[3]));
    __syncthreads();
    float ex = (t < 128) ? __expf(e - gm) : 0.f;
    float sm = ex;
#pragma unroll
    for (int off = 32; off > 0; off >>= 1) sm += __shfl_xor(sm, off);
    if (lane == 0) red[wv] = sm;
    __syncthreads();
    const float gs = red[0] + red[1] + red[2] + red[3];
    if (t < 128) {
        const float w = ex / gs;
        w_s[t] = w;
        if (s == 0) attnw[(size_t)b * L_ + t] = w;
    }
    __syncthreads();

    const int h = s * 256 + t;
    const float* encb = enc + (size_t)b * H_ + h;
    float c = 0.f;
#pragma unroll 4
    for (int l = 0; l < 128; l++)
        c += w_s[l] * encb[(size_t)l * (B_ * H_)];
    cat_hi[(size_t)b * 2048 + 1024 + h] = f2bf(c);
}

// co = tanh(sum of 4 partials + b_cat) -> bf16
__global__ __launch_bounds__(256) void co_reduce_kernel(
    const float* __restrict__ co_part, const float* __restrict__ b_cat,
    unsigned short* __restrict__ co_hi)
{
    const int id = blockIdx.x * 256 + threadIdx.x;
    const int j = id & 1023;
    float s = b_cat[j];
#pragma unroll
    for (int p = 0; p < 4; p++) s += co_part[(size_t)p * 131072 + id];
    co_hi[id] = f2bf(tanhf(s));
}

// ---------------------------------------------------------------------------
extern "C" void kernel_launch(void* const* d_in, const int* in_sizes, int n_in,
                              void* d_out, int out_size, void* d_ws, size_t ws_size,
                              hipStream_t stream)
{
    const int*   seq    = (const int*)  d_in[0];
    const float* lh     = (const float*)d_in[1];
    const float* enc    = (const float*)d_in[2];
    const int*   c2n    = (const int*)  d_in[3];
    const int*   c2f    = (const int*)  d_in[4];
    const float* emb    = (const float*)d_in[5];
    const float* semb   = (const float*)d_in[6];
    const float* nemb   = (const float*)d_in[7];
    const float* W_ih   = (const float*)d_in[8];
    const float* W_hh   = (const float*)d_in[9];
    const float* b_ih   = (const float*)d_in[10];
    const float* b_hh   = (const float*)d_in[11];
    const float* W_attn = (const float*)d_in[12];
    // d_in[13] = b_attn: dropped (softmax shift-invariant, exact)
    const float* W_cat  = (const float*)d_in[14];
    const float* b_cat  = (const float*)d_in[15];
    const float* W_out  = (const float*)d_in[16];
    const float* b_out  = (const float*)d_in[17];

    float* out    = (float*)d_out;
    float* hidden = out + (size_t)B_ * V_;
    float* attnw  = hidden + (size_t)B_ * H_;

    // ---- workspace layout ----
    unsigned short* x_hi   = (unsigned short*)d_ws;            // 128*1088
    unsigned short* x_lo   = x_hi   + (size_t)128 * INDIM;
    unsigned short* h_hi   = x_lo   + (size_t)128 * INDIM;     // 128*1024
    unsigned short* h_lo   = h_hi   + (size_t)128 * 1024;
    unsigned short* cat_hi = h_lo   + (size_t)128 * 1024;      // 128*2048
    unsigned short* cat_lo = cat_hi + (size_t)128 * 2048;
    unsigned short* co_hi  = cat_lo + (size_t)128 * 2048;      // 128*1024
    float* fbase   = (float*)(co_hi + (size_t)128 * 1024);
    float* gi_part = fbase;                                    // 4*128*3072
    float* gh_part = gi_part + (size_t)4 * 128 * 3072;         // 4*128*3072
    // aliases (gi/gh dead after gates):
    float* q_part  = fbase;                                    // 4*128*1024
    float* co_part = q_part + (size_t)4 * 128 * 1024;          // 4*128*1024
    float* epart   = co_part + (size_t)4 * 128 * 1024;         // 128*128*4

    const int SMEM_SPLIT = 55296;
    const int SMEM_PLAIN = 27648;

    // 1. prep: x, h bf16 hi/lo planes
    hipLaunchKernelGGL(prep_kernel, dim3(B_), dim3(256), 0, stream,
                       seq, c2n, c2f, emb, semb, nemb, lh, x_hi, x_lo, h_hi, h_lo);
    // 2+3. gi & gh partials in one dispatch (z selects)
    hipLaunchKernelGGL(gru_gemm, dim3(48, 4, 2), dim3(256), SMEM_SPLIT, stream,
                       x_hi, x_lo, W_ih, h_hi, h_lo, W_hh, gi_part, gh_part);
    // 4. gates -> hidden + cat planes
    hipLaunchKernelGGL(gru_gates_kernel, dim3(512), dim3(256), 0, stream,
                       gi_part, gh_part, b_ih, b_hh, lh, hidden, cat_hi, cat_lo);
    // 5. q partials = h @ W_attn (NT, split): K=1024 -> 4 x 256
    hipLaunchKernelGGL((sgemm<false, true, false>), dim3(16, 4), dim3(256), SMEM_SPLIT, stream,
                       cat_hi, cat_lo, 2048, W_attn, H_, (const float*)nullptr,
                       q_part, H_, (size_t)128 * 1024, H_, 256, 256);
    // 6. energies
    hipLaunchKernelGGL(energy_partial_kernel, dim3(4, 128), dim3(512), 0, stream,
                       q_part, enc, epart);
    // 7. softmax + context fused
    hipLaunchKernelGGL(context_softmax_kernel, dim3(4, 128), dim3(256), 0, stream,
                       epart, enc, cat_hi, attnw);
    // 8. co partials = cat @ W_cat.T: K=2048 -> 4 x 512
    hipLaunchKernelGGL((sgemm<true, false, false>), dim3(16, 4), dim3(256), SMEM_PLAIN, stream,
                       cat_hi, cat_hi, 2048, W_cat, 2048, (const float*)nullptr,
                       co_part, H_, (size_t)128 * 1024, H_, 512, 512);
    // 9. co = tanh(sum + b_cat) -> bf16
    hipLaunchKernelGGL(co_reduce_kernel, dim3(512), dim3(256), 0, stream,
                       co_part, b_cat, co_hi);
    // 10. out = co @ W_out.T + b_out — corrected async pipeline
    hipLaunchKernelGGL(out_gemm3, dim3((V_ + 63) / 64), dim3(256), 0, stream,
                       co_hi, W_out, b_out, out);
}